// Round 2
// baseline (611.812 us; speedup 1.0000x reference)
//
#include <hip/hip_runtime.h>
#include <math.h>

#define NVERT 5023
#define NV3   15069
#define NEXP  50
#define NPF   36
#define NJ    5

// ws layout (floats): [0..749] JSD[j][k][e] = j*150 + k*50 + e
//                     [750..764] JT[j*3+k]

__global__ __launch_bounds__(160) void k_jreg(const float* __restrict__ Jr,
                                              const float* __restrict__ sd,
                                              const float* __restrict__ vt,
                                              float* __restrict__ ws) {
  int j = blockIdx.x, vc = blockIdx.y, t = threadIdx.x;
  if (t >= 153) return;
  const float* base;
  int stride, oidx;
  if (t < 150) {                       // (k,e) pair: reduce J . shapedirs[:,k,100+e]
    int k = t / 50, e = t - k * 50;
    base = sd + k * 150 + 100 + e;
    stride = 450;
    oidx = j * 150 + t;
  } else {                             // k = t-150: reduce J . v_template[:,k]
    int k = t - 150;
    base = vt + k;
    stride = 3;
    oidx = 750 + j * 3 + k;
  }
  int v0 = vc * 628;
  int v1 = min(NVERT, v0 + 628);
  const float* Jrow = Jr + j * NVERT;
  float acc = 0.f;
  for (int v = v0; v < v1; ++v)
    acc = fmaf(Jrow[v], base[(size_t)v * stride], acc);
  atomicAdd(&ws[oidx], acc);
}

// one thread per batch: Rodrigues, pose_feature, joints (via JSD), FK, A
__global__ __launch_bounds__(256) void k_pose(const float* __restrict__ expr,
                                              const float* __restrict__ pose,
                                              const float* __restrict__ ws,
                                              float* __restrict__ out_pf,
                                              float* __restrict__ out_A,
                                              int B) {
  int b = blockIdx.x * 256 + threadIdx.x;
  if (b >= B) return;

  float R[5][9];
#pragma unroll
  for (int j = 0; j < 5; ++j) {
    float x = pose[b * 15 + j * 3 + 0];
    float y = pose[b * 15 + j * 3 + 1];
    float z = pose[b * 15 + j * 3 + 2];
    float ax = x + 1e-8f, ay = y + 1e-8f, az = z + 1e-8f;
    float ang = sqrtf(ax * ax + ay * ay + az * az);   // ref: norm(rv + 1e-8)
    float inv = 1.0f / ang;
    float ux = x * inv, uy = y * inv, uz = z * inv;   // ref: rv / angle
    float s = sinf(ang), c = cosf(ang), t1 = 1.0f - c;
    R[j][0] = 1.0f - t1 * (uy * uy + uz * uz);
    R[j][1] = t1 * ux * uy - s * uz;
    R[j][2] = t1 * ux * uz + s * uy;
    R[j][3] = t1 * ux * uy + s * uz;
    R[j][4] = 1.0f - t1 * (ux * ux + uz * uz);
    R[j][5] = t1 * uy * uz - s * ux;
    R[j][6] = t1 * ux * uz - s * uy;
    R[j][7] = t1 * uy * uz + s * ux;
    R[j][8] = 1.0f - t1 * (ux * ux + uy * uy);
  }

  // pose_feature = (R[1:] - I) flattened
#pragma unroll
  for (int j = 1; j < 5; ++j)
#pragma unroll
    for (int i = 0; i < 9; ++i)
      out_pf[b * 36 + (j - 1) * 9 + i] =
          R[j][i] - ((i == 0 || i == 4 || i == 8) ? 1.0f : 0.0f);

  // joints[j][k] = JT[j][k] + sum_e expr[b,e] * JSD[j][k][e]
  float jnt[5][3];
#pragma unroll
  for (int j = 0; j < 5; ++j)
#pragma unroll
    for (int k = 0; k < 3; ++k) jnt[j][k] = ws[750 + j * 3 + k];
  for (int e = 0; e < NEXP; ++e) {
    float ex = expr[b * NEXP + e];
#pragma unroll
    for (int j = 0; j < 5; ++j)
#pragma unroll
      for (int k = 0; k < 3; ++k)
        jnt[j][k] = fmaf(ex, ws[j * 150 + k * 50 + e], jnt[j][k]);
  }

  float* Ab = out_A + (size_t)b * 80;

  // joint 0: chain = local
  {
#pragma unroll
    for (int r = 0; r < 3; ++r) {
      float tj = R[0][r * 3 + 0] * jnt[0][0] + R[0][r * 3 + 1] * jnt[0][1] +
                 R[0][r * 3 + 2] * jnt[0][2];
      Ab[r * 4 + 0] = R[0][r * 3 + 0];
      Ab[r * 4 + 1] = R[0][r * 3 + 1];
      Ab[r * 4 + 2] = R[0][r * 3 + 2];
      Ab[r * 4 + 3] = jnt[0][r] - tj;
    }
    Ab[12] = 0.f; Ab[13] = 0.f; Ab[14] = 0.f; Ab[15] = 1.f;
  }

  // chain1 = chain0 * local1
  float C1R[9], C1t[3];
  {
    float rel[3] = {jnt[1][0] - jnt[0][0], jnt[1][1] - jnt[0][1],
                    jnt[1][2] - jnt[0][2]};
#pragma unroll
    for (int r = 0; r < 3; ++r) {
#pragma unroll
      for (int c = 0; c < 3; ++c)
        C1R[r * 3 + c] = R[0][r * 3 + 0] * R[1][0 + c] +
                         R[0][r * 3 + 1] * R[1][3 + c] +
                         R[0][r * 3 + 2] * R[1][6 + c];
      C1t[r] = R[0][r * 3 + 0] * rel[0] + R[0][r * 3 + 1] * rel[1] +
               R[0][r * 3 + 2] * rel[2] + jnt[0][r];
    }
    float* A1 = Ab + 16;
#pragma unroll
    for (int r = 0; r < 3; ++r) {
      float tj = C1R[r * 3 + 0] * jnt[1][0] + C1R[r * 3 + 1] * jnt[1][1] +
                 C1R[r * 3 + 2] * jnt[1][2];
      A1[r * 4 + 0] = C1R[r * 3 + 0];
      A1[r * 4 + 1] = C1R[r * 3 + 1];
      A1[r * 4 + 2] = C1R[r * 3 + 2];
      A1[r * 4 + 3] = C1t[r] - tj;
    }
    A1[12] = 0.f; A1[13] = 0.f; A1[14] = 0.f; A1[15] = 1.f;
  }

  // joints 2..4: parent = 1
#pragma unroll
  for (int i = 2; i < 5; ++i) {
    float rel[3] = {jnt[i][0] - jnt[1][0], jnt[i][1] - jnt[1][1],
                    jnt[i][2] - jnt[1][2]};
    float CiR[9], Cit[3];
#pragma unroll
    for (int r = 0; r < 3; ++r) {
#pragma unroll
      for (int c = 0; c < 3; ++c)
        CiR[r * 3 + c] = C1R[r * 3 + 0] * R[i][0 + c] +
                         C1R[r * 3 + 1] * R[i][3 + c] +
                         C1R[r * 3 + 2] * R[i][6 + c];
      Cit[r] = C1R[r * 3 + 0] * rel[0] + C1R[r * 3 + 1] * rel[1] +
               C1R[r * 3 + 2] * rel[2] + C1t[r];
    }
    float* Ai = Ab + i * 16;
#pragma unroll
    for (int r = 0; r < 3; ++r) {
      float tj = CiR[r * 3 + 0] * jnt[i][0] + CiR[r * 3 + 1] * jnt[i][1] +
                 CiR[r * 3 + 2] * jnt[i][2];
      Ai[r * 4 + 0] = CiR[r * 3 + 0];
      Ai[r * 4 + 1] = CiR[r * 3 + 1];
      Ai[r * 4 + 2] = CiR[r * 3 + 2];
      Ai[r * 4 + 3] = Cit[r] - tj;
    }
    Ai[12] = 0.f; Ai[13] = 0.f; Ai[14] = 0.f; Ai[15] = 1.f;
  }
}

// fused blend + skinning: thread = (vertex, component), 64 verts * 3 per block
__global__ __launch_bounds__(192) void k_vert(const float* __restrict__ expr,
                                              const float* __restrict__ vt,
                                              const float* __restrict__ sd,
                                              const float* __restrict__ pd,
                                              const float* __restrict__ w,
                                              const float* __restrict__ pf,
                                              const float* __restrict__ A,
                                              float* __restrict__ out, int B) {
  int lv = threadIdx.x / 3;
  int kc = threadIdx.x - lv * 3;
  int v = blockIdx.x * 64 + lv;
  bool act = v < NVERT;
  int vl = act ? v : NVERT - 1;

  float sdr[NEXP], pdr[NPF], wr[NJ];
  const float* sp = sd + (size_t)vl * 450 + kc * 150 + 100;
#pragma unroll
  for (int e = 0; e < NEXP; ++e) sdr[e] = sp[e];
#pragma unroll
  for (int p = 0; p < NPF; ++p) pdr[p] = pd[(size_t)p * NV3 + vl * 3 + kc];
#pragma unroll
  for (int j = 0; j < NJ; ++j) wr[j] = w[vl * 5 + j];
  float vtr = vt[vl * 3 + kc];

  __shared__ float vp[64][3];

  int b0 = blockIdx.y * 128;
  int bend = min(B, b0 + 128);
  for (int b = b0; b < bend; ++b) {
    const float* eb = expr + (size_t)b * NEXP;   // uniform -> s_load
    const float* pb = pf + (size_t)b * NPF;      // uniform -> s_load
    const float* Ab = A + (size_t)b * 80 + kc * 4;
    float acc = vtr;
#pragma unroll
    for (int e = 0; e < NEXP; ++e) acc = fmaf(eb[e], sdr[e], acc);
#pragma unroll
    for (int p = 0; p < NPF; ++p) acc = fmaf(pb[p], pdr[p], acc);
    vp[lv][kc] = acc;
    __syncthreads();
    float t0 = 0.f, t1 = 0.f, t2 = 0.f, t3 = 0.f;
#pragma unroll
    for (int j = 0; j < NJ; ++j) {
      t0 = fmaf(wr[j], Ab[j * 16 + 0], t0);
      t1 = fmaf(wr[j], Ab[j * 16 + 1], t1);
      t2 = fmaf(wr[j], Ab[j * 16 + 2], t2);
      t3 = fmaf(wr[j], Ab[j * 16 + 3], t3);
    }
    float r = fmaf(t0, vp[lv][0], fmaf(t1, vp[lv][1], fmaf(t2, vp[lv][2], t3)));
    if (act) out[(size_t)b * NV3 + v * 3 + kc] = r;
    __syncthreads();
  }
}

extern "C" void kernel_launch(void* const* d_in, const int* in_sizes, int n_in,
                              void* d_out, int out_size, void* d_ws,
                              size_t ws_size, hipStream_t stream) {
  const float* expr = (const float*)d_in[0];
  const float* pose = (const float*)d_in[1];
  const float* vt   = (const float*)d_in[2];
  const float* sd   = (const float*)d_in[3];
  const float* pd   = (const float*)d_in[4];
  const float* Jr   = (const float*)d_in[5];
  const float* w    = (const float*)d_in[6];
  int B = in_sizes[0] / NEXP;

  float* out    = (float*)d_out;
  float* out_pf = out + (size_t)B * NV3;
  float* out_A  = out_pf + (size_t)B * NPF;
  float* ws     = (float*)d_ws;

  hipMemsetAsync(d_ws, 0, 765 * sizeof(float), stream);
  k_jreg<<<dim3(5, 8), 160, 0, stream>>>(Jr, sd, vt, ws);
  k_pose<<<(B + 255) / 256, 256, 0, stream>>>(expr, pose, ws, out_pf, out_A, B);
  k_vert<<<dim3((NVERT + 63) / 64, (B + 127) / 128), 192, 0, stream>>>(
      expr, vt, sd, pd, w, out_pf, out_A, out, B);
}

// Round 4
// 399.056 us; speedup vs baseline: 1.5331x; 1.5331x over previous
//
#include <hip/hip_runtime.h>
#include <math.h>

#define NVERT 5023
#define NV3   15069
#define NEXP  50
#define NPF   36
#define NJ    5
#define BCH   128

// ws layout (floats): [0..749] JSD[j][k][e] = j*150 + k*50 + e
//                     [750..764] JT[j*3+k]

// 64 blocks x 160 threads; thread = (k,e) column (or vt column), j-loop inside.
__global__ __launch_bounds__(160) void k_jreg(const float* __restrict__ Jr,
                                              const float* __restrict__ sd,
                                              const float* __restrict__ vt,
                                              float* __restrict__ ws) {
  int t = threadIdx.x;
  int v0 = blockIdx.x * 79;
  int v1 = min(NVERT, v0 + 79);
  float acc[NJ] = {0.f, 0.f, 0.f, 0.f, 0.f};
  if (t < 150) {
    int k = t / 50, e = t - k * 50;
    const float* base = sd + k * 150 + 100 + e;
#pragma unroll 4
    for (int v = v0; v < v1; ++v) {
      float s = base[(size_t)v * 450];
#pragma unroll
      for (int j = 0; j < NJ; ++j)
        acc[j] = fmaf(Jr[j * NVERT + v], s, acc[j]);   // Jr load is uniform -> s_load
    }
#pragma unroll
    for (int j = 0; j < NJ; ++j) atomicAdd(&ws[j * 150 + t], acc[j]);
  } else if (t < 153) {
    int k = t - 150;
#pragma unroll 4
    for (int v = v0; v < v1; ++v) {
      float s = vt[v * 3 + k];
#pragma unroll
      for (int j = 0; j < NJ; ++j)
        acc[j] = fmaf(Jr[j * NVERT + v], s, acc[j]);
    }
#pragma unroll
    for (int j = 0; j < NJ; ++j) atomicAdd(&ws[750 + j * 3 + k], acc[j]);
  }
}

// one thread per batch: Rodrigues, pose_feature, joints (via JSD), FK, A
__global__ __launch_bounds__(256) void k_pose(const float* __restrict__ expr,
                                              const float* __restrict__ pose,
                                              const float* __restrict__ ws,
                                              float* __restrict__ out_pf,
                                              float* __restrict__ out_A,
                                              int B) {
  int b = blockIdx.x * 256 + threadIdx.x;
  if (b >= B) return;

  float R[5][9];
#pragma unroll
  for (int j = 0; j < 5; ++j) {
    float x = pose[b * 15 + j * 3 + 0];
    float y = pose[b * 15 + j * 3 + 1];
    float z = pose[b * 15 + j * 3 + 2];
    float ax = x + 1e-8f, ay = y + 1e-8f, az = z + 1e-8f;
    float ang = sqrtf(ax * ax + ay * ay + az * az);   // ref: norm(rv + 1e-8)
    float inv = 1.0f / ang;
    float ux = x * inv, uy = y * inv, uz = z * inv;   // ref: rv / angle
    float s = sinf(ang), c = cosf(ang), t1 = 1.0f - c;
    R[j][0] = 1.0f - t1 * (uy * uy + uz * uz);
    R[j][1] = t1 * ux * uy - s * uz;
    R[j][2] = t1 * ux * uz + s * uy;
    R[j][3] = t1 * ux * uy + s * uz;
    R[j][4] = 1.0f - t1 * (ux * ux + uz * uz);
    R[j][5] = t1 * uy * uz - s * ux;
    R[j][6] = t1 * ux * uz - s * uy;
    R[j][7] = t1 * uy * uz + s * ux;
    R[j][8] = 1.0f - t1 * (ux * ux + uy * uy);
  }

#pragma unroll
  for (int j = 1; j < 5; ++j)
#pragma unroll
    for (int i = 0; i < 9; ++i)
      out_pf[b * 36 + (j - 1) * 9 + i] =
          R[j][i] - ((i == 0 || i == 4 || i == 8) ? 1.0f : 0.0f);

  float jnt[5][3];
#pragma unroll
  for (int j = 0; j < 5; ++j)
#pragma unroll
    for (int k = 0; k < 3; ++k) jnt[j][k] = ws[750 + j * 3 + k];
  for (int e = 0; e < NEXP; ++e) {
    float ex = expr[b * NEXP + e];
#pragma unroll
    for (int j = 0; j < 5; ++j)
#pragma unroll
      for (int k = 0; k < 3; ++k)
        jnt[j][k] = fmaf(ex, ws[j * 150 + k * 50 + e], jnt[j][k]);
  }

  float* Ab = out_A + (size_t)b * 80;

  {
#pragma unroll
    for (int r = 0; r < 3; ++r) {
      float tj = R[0][r * 3 + 0] * jnt[0][0] + R[0][r * 3 + 1] * jnt[0][1] +
                 R[0][r * 3 + 2] * jnt[0][2];
      Ab[r * 4 + 0] = R[0][r * 3 + 0];
      Ab[r * 4 + 1] = R[0][r * 3 + 1];
      Ab[r * 4 + 2] = R[0][r * 3 + 2];
      Ab[r * 4 + 3] = jnt[0][r] - tj;
    }
    Ab[12] = 0.f; Ab[13] = 0.f; Ab[14] = 0.f; Ab[15] = 1.f;
  }

  float C1R[9], C1t[3];
  {
    float rel[3] = {jnt[1][0] - jnt[0][0], jnt[1][1] - jnt[0][1],
                    jnt[1][2] - jnt[0][2]};
#pragma unroll
    for (int r = 0; r < 3; ++r) {
#pragma unroll
      for (int c = 0; c < 3; ++c)
        C1R[r * 3 + c] = R[0][r * 3 + 0] * R[1][0 + c] +
                         R[0][r * 3 + 1] * R[1][3 + c] +
                         R[0][r * 3 + 2] * R[1][6 + c];
      C1t[r] = R[0][r * 3 + 0] * rel[0] + R[0][r * 3 + 1] * rel[1] +
               R[0][r * 3 + 2] * rel[2] + jnt[0][r];
    }
    float* A1 = Ab + 16;
#pragma unroll
    for (int r = 0; r < 3; ++r) {
      float tj = C1R[r * 3 + 0] * jnt[1][0] + C1R[r * 3 + 1] * jnt[1][1] +
                 C1R[r * 3 + 2] * jnt[1][2];
      A1[r * 4 + 0] = C1R[r * 3 + 0];
      A1[r * 4 + 1] = C1R[r * 3 + 1];
      A1[r * 4 + 2] = C1R[r * 3 + 2];
      A1[r * 4 + 3] = C1t[r] - tj;
    }
    A1[12] = 0.f; A1[13] = 0.f; A1[14] = 0.f; A1[15] = 1.f;
  }

#pragma unroll
  for (int i = 2; i < 5; ++i) {
    float rel[3] = {jnt[i][0] - jnt[1][0], jnt[i][1] - jnt[1][1],
                    jnt[i][2] - jnt[1][2]};
    float CiR[9], Cit[3];
#pragma unroll
    for (int r = 0; r < 3; ++r) {
#pragma unroll
      for (int c = 0; c < 3; ++c)
        CiR[r * 3 + c] = C1R[r * 3 + 0] * R[i][0 + c] +
                         C1R[r * 3 + 1] * R[i][3 + c] +
                         C1R[r * 3 + 2] * R[i][6 + c];
      Cit[r] = C1R[r * 3 + 0] * rel[0] + C1R[r * 3 + 1] * rel[1] +
               C1R[r * 3 + 2] * rel[2] + C1t[r];
    }
    float* Ai = Ab + i * 16;
#pragma unroll
    for (int r = 0; r < 3; ++r) {
      float tj = CiR[r * 3 + 0] * jnt[i][0] + CiR[r * 3 + 1] * jnt[i][1] +
                 CiR[r * 3 + 2] * jnt[i][2];
      Ai[r * 4 + 0] = CiR[r * 3 + 0];
      Ai[r * 4 + 1] = CiR[r * 3 + 1];
      Ai[r * 4 + 2] = CiR[r * 3 + 2];
      Ai[r * 4 + 3] = Cit[r] - tj;
    }
    Ai[12] = 0.f; Ai[13] = 0.f; Ai[14] = 0.f; Ai[15] = 1.f;
  }
}

// fused blend + skinning, barrier-free: each wave owns 21 verts x 3 comps
// in lanes 0..62 (lane 63 idle); v_posed transpose via 3 intra-wave shuffles.
__global__ __launch_bounds__(256) void k_vert(const float* __restrict__ expr,
                                              const float* __restrict__ vt,
                                              const float* __restrict__ sd,
                                              const float* __restrict__ pd,
                                              const float* __restrict__ w,
                                              const float* __restrict__ pf,
                                              const float* __restrict__ A,
                                              float* __restrict__ out, int B) {
  int wv = threadIdx.x >> 6;
  int lane = threadIdx.x & 63;
  int lvw = lane / 3;          // 0..21 (21 only at lane 63)
  int kc = lane - lvw * 3;
  int v = blockIdx.x * 84 + wv * 21 + lvw;
  bool act = (lane < 63) && (v < NVERT);
  int vl = act ? v : 0;
  int srcb = lane - kc;        // lane of kc==0 in this vertex triplet

  float sdr[NEXP], pdr[NPF], wr[NJ];
  const float* sp = sd + (size_t)vl * 450 + kc * 150 + 100;
#pragma unroll
  for (int e = 0; e < NEXP; ++e) sdr[e] = sp[e];
#pragma unroll
  for (int p = 0; p < NPF; ++p) pdr[p] = pd[(size_t)p * NV3 + vl * 3 + kc];
#pragma unroll
  for (int j = 0; j < NJ; ++j) wr[j] = w[vl * 5 + j];
  float vtr = vt[vl * 3 + kc];

  int b0 = blockIdx.y * BCH;
  int bend = min(B, b0 + BCH);
  for (int b = b0; b < bend; ++b) {
    const float* eb = expr + (size_t)b * NEXP;       // uniform -> s_load
    const float* pb = pf + (size_t)b * NPF;          // uniform -> s_load
    const float4* A4 = (const float4*)(A + (size_t)b * 80);
    // blend: 4 independent accumulator chains for ILP
    float a0 = 0.f, a1 = 0.f, a2 = 0.f, a3 = 0.f;
#pragma unroll
    for (int e = 0; e < 48; e += 4) {
      a0 = fmaf(eb[e + 0], sdr[e + 0], a0);
      a1 = fmaf(eb[e + 1], sdr[e + 1], a1);
      a2 = fmaf(eb[e + 2], sdr[e + 2], a2);
      a3 = fmaf(eb[e + 3], sdr[e + 3], a3);
    }
    a0 = fmaf(eb[48], sdr[48], a0);
    a1 = fmaf(eb[49], sdr[49], a1);
#pragma unroll
    for (int p = 0; p < 36; p += 4) {
      a0 = fmaf(pb[p + 0], pdr[p + 0], a0);
      a1 = fmaf(pb[p + 1], pdr[p + 1], a1);
      a2 = fmaf(pb[p + 2], pdr[p + 2], a2);
      a3 = fmaf(pb[p + 3], pdr[p + 3], a3);
    }
    float acc = vtr + ((a0 + a1) + (a2 + a3));
    // transpose within the vertex triplet (no divergence before here)
    float x0 = __shfl(acc, srcb + 0, 64);
    float x1 = __shfl(acc, srcb + 1, 64);
    float x2 = __shfl(acc, srcb + 2, 64);
    // T row kc = sum_j w_j * A[b][j][kc][:]
    float t0 = 0.f, t1 = 0.f, t2 = 0.f, t3 = 0.f;
#pragma unroll
    for (int j = 0; j < NJ; ++j) {
      float4 aj = A4[j * 4 + kc];
      t0 = fmaf(wr[j], aj.x, t0);
      t1 = fmaf(wr[j], aj.y, t1);
      t2 = fmaf(wr[j], aj.z, t2);
      t3 = fmaf(wr[j], aj.w, t3);
    }
    float r = fmaf(t0, x0, fmaf(t1, x1, fmaf(t2, x2, t3)));
    if (act) out[(size_t)b * NV3 + (size_t)v * 3 + kc] = r;
  }
}

extern "C" void kernel_launch(void* const* d_in, const int* in_sizes, int n_in,
                              void* d_out, int out_size, void* d_ws,
                              size_t ws_size, hipStream_t stream) {
  const float* expr = (const float*)d_in[0];
  const float* pose = (const float*)d_in[1];
  const float* vt   = (const float*)d_in[2];
  const float* sd   = (const float*)d_in[3];
  const float* pd   = (const float*)d_in[4];
  const float* Jr   = (const float*)d_in[5];
  const float* w    = (const float*)d_in[6];
  int B = in_sizes[0] / NEXP;

  float* out    = (float*)d_out;
  float* out_pf = out + (size_t)B * NV3;
  float* out_A  = out_pf + (size_t)B * NPF;
  float* ws     = (float*)d_ws;

  hipMemsetAsync(d_ws, 0, 765 * sizeof(float), stream);
  k_jreg<<<dim3(64), 160, 0, stream>>>(Jr, sd, vt, ws);
  k_pose<<<(B + 255) / 256, 256, 0, stream>>>(expr, pose, ws, out_pf, out_A, B);
  k_vert<<<dim3((NVERT + 83) / 84, (B + BCH - 1) / BCH), 256, 0, stream>>>(
      expr, vt, sd, pd, w, out_pf, out_A, out, B);
}

// Round 5
// 391.829 us; speedup vs baseline: 1.5614x; 1.0184x over previous
//
#include <hip/hip_runtime.h>
#include <math.h>

#define NVERT 5023
#define NV3   15069
#define NEXP  50
#define NPF   36
#define NJ    5
#define BCH   64
#define JCH   40   // verts per k_jreg block -> 126 blocks

// ws layout (floats): [0..749] JSD[j][k][e] = j*150 + k*50 + e
//                     [750..764] JT[j*3+k]

// 126 blocks x 160 threads; thread = (k,e) column (or vt column), j-loop inside.
// 4 loads kept in flight; atomics: one per (block, address).
__global__ __launch_bounds__(160) void k_jreg(const float* __restrict__ Jr,
                                              const float* __restrict__ sd,
                                              const float* __restrict__ vt,
                                              float* __restrict__ ws) {
  int t = threadIdx.x;
  int v0 = blockIdx.x * JCH;
  int v1 = min(NVERT, v0 + JCH);
  float acc[NJ] = {0.f, 0.f, 0.f, 0.f, 0.f};
  if (t < 150) {
    int k = t / 50, e = t - k * 50;
    const float* base = sd + k * 150 + 100 + e;
    int v = v0;
    for (; v + 4 <= v1; v += 4) {
      float s0 = base[(size_t)(v + 0) * 450];
      float s1 = base[(size_t)(v + 1) * 450];
      float s2 = base[(size_t)(v + 2) * 450];
      float s3 = base[(size_t)(v + 3) * 450];
#pragma unroll
      for (int j = 0; j < NJ; ++j) {
        acc[j] = fmaf(Jr[j * NVERT + v + 0], s0, acc[j]);
        acc[j] = fmaf(Jr[j * NVERT + v + 1], s1, acc[j]);
        acc[j] = fmaf(Jr[j * NVERT + v + 2], s2, acc[j]);
        acc[j] = fmaf(Jr[j * NVERT + v + 3], s3, acc[j]);
      }
    }
    for (; v < v1; ++v) {
      float s = base[(size_t)v * 450];
#pragma unroll
      for (int j = 0; j < NJ; ++j)
        acc[j] = fmaf(Jr[j * NVERT + v], s, acc[j]);
    }
#pragma unroll
    for (int j = 0; j < NJ; ++j) atomicAdd(&ws[j * 150 + t], acc[j]);
  } else if (t < 153) {
    int k = t - 150;
    int v = v0;
    for (; v + 4 <= v1; v += 4) {
      float s0 = vt[(v + 0) * 3 + k];
      float s1 = vt[(v + 1) * 3 + k];
      float s2 = vt[(v + 2) * 3 + k];
      float s3 = vt[(v + 3) * 3 + k];
#pragma unroll
      for (int j = 0; j < NJ; ++j) {
        acc[j] = fmaf(Jr[j * NVERT + v + 0], s0, acc[j]);
        acc[j] = fmaf(Jr[j * NVERT + v + 1], s1, acc[j]);
        acc[j] = fmaf(Jr[j * NVERT + v + 2], s2, acc[j]);
        acc[j] = fmaf(Jr[j * NVERT + v + 3], s3, acc[j]);
      }
    }
    for (; v < v1; ++v) {
      float s = vt[v * 3 + k];
#pragma unroll
      for (int j = 0; j < NJ; ++j)
        acc[j] = fmaf(Jr[j * NVERT + v], s, acc[j]);
    }
#pragma unroll
    for (int j = 0; j < NJ; ++j) atomicAdd(&ws[750 + j * 3 + k], acc[j]);
  }
}

// one thread per batch: Rodrigues, pose_feature, joints (via JSD), FK, A
__global__ __launch_bounds__(256) void k_pose(const float* __restrict__ expr,
                                              const float* __restrict__ pose,
                                              const float* __restrict__ ws,
                                              float* __restrict__ out_pf,
                                              float* __restrict__ out_A,
                                              int B) {
  int b = blockIdx.x * 256 + threadIdx.x;
  if (b >= B) return;

  float R[5][9];
#pragma unroll
  for (int j = 0; j < 5; ++j) {
    float x = pose[b * 15 + j * 3 + 0];
    float y = pose[b * 15 + j * 3 + 1];
    float z = pose[b * 15 + j * 3 + 2];
    float ax = x + 1e-8f, ay = y + 1e-8f, az = z + 1e-8f;
    float ang = sqrtf(ax * ax + ay * ay + az * az);   // ref: norm(rv + 1e-8)
    float inv = 1.0f / ang;
    float ux = x * inv, uy = y * inv, uz = z * inv;   // ref: rv / angle
    float s = sinf(ang), c = cosf(ang), t1 = 1.0f - c;
    R[j][0] = 1.0f - t1 * (uy * uy + uz * uz);
    R[j][1] = t1 * ux * uy - s * uz;
    R[j][2] = t1 * ux * uz + s * uy;
    R[j][3] = t1 * ux * uy + s * uz;
    R[j][4] = 1.0f - t1 * (ux * ux + uz * uz);
    R[j][5] = t1 * uy * uz - s * ux;
    R[j][6] = t1 * ux * uz - s * uy;
    R[j][7] = t1 * uy * uz + s * ux;
    R[j][8] = 1.0f - t1 * (ux * ux + uy * uy);
  }

#pragma unroll
  for (int j = 1; j < 5; ++j)
#pragma unroll
    for (int i = 0; i < 9; ++i)
      out_pf[b * 36 + (j - 1) * 9 + i] =
          R[j][i] - ((i == 0 || i == 4 || i == 8) ? 1.0f : 0.0f);

  float jnt[5][3];
#pragma unroll
  for (int j = 0; j < 5; ++j)
#pragma unroll
    for (int k = 0; k < 3; ++k) jnt[j][k] = ws[750 + j * 3 + k];
  for (int e = 0; e < NEXP; ++e) {
    float ex = expr[b * NEXP + e];
#pragma unroll
    for (int j = 0; j < 5; ++j)
#pragma unroll
      for (int k = 0; k < 3; ++k)
        jnt[j][k] = fmaf(ex, ws[j * 150 + k * 50 + e], jnt[j][k]);
  }

  float* Ab = out_A + (size_t)b * 80;

  {
#pragma unroll
    for (int r = 0; r < 3; ++r) {
      float tj = R[0][r * 3 + 0] * jnt[0][0] + R[0][r * 3 + 1] * jnt[0][1] +
                 R[0][r * 3 + 2] * jnt[0][2];
      Ab[r * 4 + 0] = R[0][r * 3 + 0];
      Ab[r * 4 + 1] = R[0][r * 3 + 1];
      Ab[r * 4 + 2] = R[0][r * 3 + 2];
      Ab[r * 4 + 3] = jnt[0][r] - tj;
    }
    Ab[12] = 0.f; Ab[13] = 0.f; Ab[14] = 0.f; Ab[15] = 1.f;
  }

  float C1R[9], C1t[3];
  {
    float rel[3] = {jnt[1][0] - jnt[0][0], jnt[1][1] - jnt[0][1],
                    jnt[1][2] - jnt[0][2]};
#pragma unroll
    for (int r = 0; r < 3; ++r) {
#pragma unroll
      for (int c = 0; c < 3; ++c)
        C1R[r * 3 + c] = R[0][r * 3 + 0] * R[1][0 + c] +
                         R[0][r * 3 + 1] * R[1][3 + c] +
                         R[0][r * 3 + 2] * R[1][6 + c];
      C1t[r] = R[0][r * 3 + 0] * rel[0] + R[0][r * 3 + 1] * rel[1] +
               R[0][r * 3 + 2] * rel[2] + jnt[0][r];
    }
    float* A1 = Ab + 16;
#pragma unroll
    for (int r = 0; r < 3; ++r) {
      float tj = C1R[r * 3 + 0] * jnt[1][0] + C1R[r * 3 + 1] * jnt[1][1] +
                 C1R[r * 3 + 2] * jnt[1][2];
      A1[r * 4 + 0] = C1R[r * 3 + 0];
      A1[r * 4 + 1] = C1R[r * 3 + 1];
      A1[r * 4 + 2] = C1R[r * 3 + 2];
      A1[r * 4 + 3] = C1t[r] - tj;
    }
    A1[12] = 0.f; A1[13] = 0.f; A1[14] = 0.f; A1[15] = 1.f;
  }

#pragma unroll
  for (int i = 2; i < 5; ++i) {
    float rel[3] = {jnt[i][0] - jnt[1][0], jnt[i][1] - jnt[1][1],
                    jnt[i][2] - jnt[1][2]};
    float CiR[9], Cit[3];
#pragma unroll
    for (int r = 0; r < 3; ++r) {
#pragma unroll
      for (int c = 0; c < 3; ++c)
        CiR[r * 3 + c] = C1R[r * 3 + 0] * R[i][0 + c] +
                         C1R[r * 3 + 1] * R[i][3 + c] +
                         C1R[r * 3 + 2] * R[i][6 + c];
      Cit[r] = C1R[r * 3 + 0] * rel[0] + C1R[r * 3 + 1] * rel[1] +
               C1R[r * 3 + 2] * rel[2] + C1t[r];
    }
    float* Ai = Ab + i * 16;
#pragma unroll
    for (int r = 0; r < 3; ++r) {
      float tj = CiR[r * 3 + 0] * jnt[i][0] + CiR[r * 3 + 1] * jnt[i][1] +
                 CiR[r * 3 + 2] * jnt[i][2];
      Ai[r * 4 + 0] = CiR[r * 3 + 0];
      Ai[r * 4 + 1] = CiR[r * 3 + 1];
      Ai[r * 4 + 2] = CiR[r * 3 + 2];
      Ai[r * 4 + 3] = Cit[r] - tj;
    }
    Ai[12] = 0.f; Ai[13] = 0.f; Ai[14] = 0.f; Ai[15] = 1.f;
  }
}

// fused blend + skinning. Lane = (vertex, component) triplets within a wave.
// Blend coefficients PINNED in VGPRs via opaque asm (stops compiler remat /
// per-iteration L1 re-reads, which round-4 profiling showed was the
// bottleneck: VGPR_Count=64 < 92 preloaded floats).
__global__ __launch_bounds__(256, 4) void k_vert(const float* __restrict__ expr,
                                                 const float* __restrict__ vt,
                                                 const float* __restrict__ sd,
                                                 const float* __restrict__ pd,
                                                 const float* __restrict__ w,
                                                 const float* __restrict__ pf,
                                                 const float* __restrict__ A,
                                                 float* __restrict__ out, int B) {
  int wv = threadIdx.x >> 6;
  int lane = threadIdx.x & 63;
  int lvw = lane / 3;          // 0..21 (21 only at lane 63)
  int kc = lane - lvw * 3;
  int v = blockIdx.x * 84 + wv * 21 + lvw;
  bool act = (lane < 63) && (v < NVERT);
  int vl = act ? v : 0;
  int srcb = lane - kc;        // lane of kc==0 in this vertex triplet

  float sdr[NEXP], pdr[NPF], wr[NJ];
  const float* sp = sd + (size_t)vl * 450 + kc * 150 + 100;
#pragma unroll
  for (int e = 0; e < NEXP; ++e) sdr[e] = sp[e];
#pragma unroll
  for (int p = 0; p < NPF; ++p) pdr[p] = pd[(size_t)p * NV3 + vl * 3 + kc];
#pragma unroll
  for (int j = 0; j < NJ; ++j) wr[j] = w[vl * 5 + j];
  float vtr = vt[vl * 3 + kc];

  // pin all preloaded coefficients into VGPRs (opaque to the optimizer)
#pragma unroll
  for (int e = 0; e < NEXP; ++e) asm volatile("" : "+v"(sdr[e]));
#pragma unroll
  for (int p = 0; p < NPF; ++p) asm volatile("" : "+v"(pdr[p]));
#pragma unroll
  for (int j = 0; j < NJ; ++j) asm volatile("" : "+v"(wr[j]));
  asm volatile("" : "+v"(vtr));

  int b0 = blockIdx.y * BCH;
  int bend = min(B, b0 + BCH);
  float* op = out + (size_t)b0 * NV3 + (size_t)v * 3 + kc;
  for (int b = b0; b < bend; ++b, op += NV3) {
    const float* eb = expr + (size_t)b * NEXP;       // uniform -> s_load
    const float* pb = pf + (size_t)b * NPF;          // uniform -> s_load
    const float4* A4 = (const float4*)(A + (size_t)b * 80);
    // issue A loads early; latency hides under the 86-FMA blend
    float4 Aj0 = A4[0 * 4 + kc];
    float4 Aj1 = A4[1 * 4 + kc];
    float4 Aj2 = A4[2 * 4 + kc];
    float4 Aj3 = A4[3 * 4 + kc];
    float4 Aj4 = A4[4 * 4 + kc];
    // blend: 4 independent accumulator chains for ILP
    float a0 = 0.f, a1 = 0.f, a2 = 0.f, a3 = 0.f;
#pragma unroll
    for (int e = 0; e < 48; e += 4) {
      a0 = fmaf(eb[e + 0], sdr[e + 0], a0);
      a1 = fmaf(eb[e + 1], sdr[e + 1], a1);
      a2 = fmaf(eb[e + 2], sdr[e + 2], a2);
      a3 = fmaf(eb[e + 3], sdr[e + 3], a3);
    }
    a0 = fmaf(eb[48], sdr[48], a0);
    a1 = fmaf(eb[49], sdr[49], a1);
#pragma unroll
    for (int p = 0; p < 36; p += 4) {
      a0 = fmaf(pb[p + 0], pdr[p + 0], a0);
      a1 = fmaf(pb[p + 1], pdr[p + 1], a1);
      a2 = fmaf(pb[p + 2], pdr[p + 2], a2);
      a3 = fmaf(pb[p + 3], pdr[p + 3], a3);
    }
    float acc = vtr + ((a0 + a1) + (a2 + a3));
    // transpose within the vertex triplet
    float x0 = __shfl(acc, srcb + 0, 64);
    float x1 = __shfl(acc, srcb + 1, 64);
    float x2 = __shfl(acc, srcb + 2, 64);
    // T row kc = sum_j w_j * A[b][j][kc][:]
    float t0 = wr[0] * Aj0.x, t1 = wr[0] * Aj0.y,
          t2 = wr[0] * Aj0.z, t3 = wr[0] * Aj0.w;
    t0 = fmaf(wr[1], Aj1.x, t0); t1 = fmaf(wr[1], Aj1.y, t1);
    t2 = fmaf(wr[1], Aj1.z, t2); t3 = fmaf(wr[1], Aj1.w, t3);
    t0 = fmaf(wr[2], Aj2.x, t0); t1 = fmaf(wr[2], Aj2.y, t1);
    t2 = fmaf(wr[2], Aj2.z, t2); t3 = fmaf(wr[2], Aj2.w, t3);
    t0 = fmaf(wr[3], Aj3.x, t0); t1 = fmaf(wr[3], Aj3.y, t1);
    t2 = fmaf(wr[3], Aj3.z, t2); t3 = fmaf(wr[3], Aj3.w, t3);
    t0 = fmaf(wr[4], Aj4.x, t0); t1 = fmaf(wr[4], Aj4.y, t1);
    t2 = fmaf(wr[4], Aj4.z, t2); t3 = fmaf(wr[4], Aj4.w, t3);
    float r = fmaf(t0, x0, fmaf(t1, x1, fmaf(t2, x2, t3)));
    if (act) *op = r;
  }
}

extern "C" void kernel_launch(void* const* d_in, const int* in_sizes, int n_in,
                              void* d_out, int out_size, void* d_ws,
                              size_t ws_size, hipStream_t stream) {
  const float* expr = (const float*)d_in[0];
  const float* pose = (const float*)d_in[1];
  const float* vt   = (const float*)d_in[2];
  const float* sd   = (const float*)d_in[3];
  const float* pd   = (const float*)d_in[4];
  const float* Jr   = (const float*)d_in[5];
  const float* w    = (const float*)d_in[6];
  int B = in_sizes[0] / NEXP;

  float* out    = (float*)d_out;
  float* out_pf = out + (size_t)B * NV3;
  float* out_A  = out_pf + (size_t)B * NPF;
  float* ws     = (float*)d_ws;

  hipMemsetAsync(d_ws, 0, 765 * sizeof(float), stream);
  k_jreg<<<dim3((NVERT + JCH - 1) / JCH), 160, 0, stream>>>(Jr, sd, vt, ws);
  k_pose<<<(B + 255) / 256, 256, 0, stream>>>(expr, pose, ws, out_pf, out_A, B);
  k_vert<<<dim3((NVERT + 83) / 84, (B + BCH - 1) / BCH), 256, 0, stream>>>(
      expr, vt, sd, pd, w, out_pf, out_A, out, B);
}

// Round 10
// 390.458 us; speedup vs baseline: 1.5669x; 1.0035x over previous
//
#include <hip/hip_runtime.h>
#include <math.h>

#define NVERT 5023
#define NV3   15069
#define NEXP  50
#define NPF   36
#define NJ    5

// ws float layout:
//   part: [0 .. 126*800)            part[blk*800 + j*160 + t], t in 0..152
//   wsJ:  [100800 .. 100800+800)    wsJ[j*160 + t]:
//         t<150: JSD[j][k][e] at t=k*50+e ; t=150..152: JT[j][k] at 150+k
#define JBLK 126
#define JCH  40
#define PSTR 800
#define WSJ  (JBLK * PSTR)

__global__ __launch_bounds__(160) void k_jreg(const float* __restrict__ Jr,
                                              const float* __restrict__ sd,
                                              const float* __restrict__ vt,
                                              float* __restrict__ ws) {
  int t = threadIdx.x;
  if (t >= 153) return;
  int v0 = blockIdx.x * JCH;
  int v1 = min(NVERT, v0 + JCH);
  float acc[NJ] = {0.f, 0.f, 0.f, 0.f, 0.f};
  float* pb = ws + blockIdx.x * PSTR;
  if (t < 150) {
    int k = t / 50, e = t - k * 50;
    const float* base = sd + k * 150 + 100 + e;
    int v = v0;
    for (; v + 4 <= v1; v += 4) {
      float s0 = base[(size_t)(v + 0) * 450];
      float s1 = base[(size_t)(v + 1) * 450];
      float s2 = base[(size_t)(v + 2) * 450];
      float s3 = base[(size_t)(v + 3) * 450];
#pragma unroll
      for (int j = 0; j < NJ; ++j) {
        acc[j] = fmaf(Jr[j * NVERT + v + 0], s0, acc[j]);
        acc[j] = fmaf(Jr[j * NVERT + v + 1], s1, acc[j]);
        acc[j] = fmaf(Jr[j * NVERT + v + 2], s2, acc[j]);
        acc[j] = fmaf(Jr[j * NVERT + v + 3], s3, acc[j]);
      }
    }
    for (; v < v1; ++v) {
      float s = base[(size_t)v * 450];
#pragma unroll
      for (int j = 0; j < NJ; ++j)
        acc[j] = fmaf(Jr[j * NVERT + v], s, acc[j]);
    }
#pragma unroll
    for (int j = 0; j < NJ; ++j) pb[j * 160 + t] = acc[j];
  } else {
    int k = t - 150;
    for (int v = v0; v < v1; ++v) {
      float s = vt[v * 3 + k];
#pragma unroll
      for (int j = 0; j < NJ; ++j)
        acc[j] = fmaf(Jr[j * NVERT + v], s, acc[j]);
    }
#pragma unroll
    for (int j = 0; j < NJ; ++j) pb[j * 160 + 150 + k] = acc[j];
  }
}

__global__ __launch_bounds__(256) void k_jred(float* __restrict__ ws) {
  int o = blockIdx.x * 256 + threadIdx.x;
  if (o >= 765) return;
  int j = o / 153, t = o - j * 153;
  int off = j * 160 + t;
  float s = 0.f;
#pragma unroll 6
  for (int bk = 0; bk < JBLK; ++bk) s += ws[bk * PSTR + off];
  ws[WSJ + off] = s;
}

// one thread per batch; 64-thread blocks; coalesced stores via LDS transpose
__global__ __launch_bounds__(64) void k_pose(const float* __restrict__ expr,
                                             const float* __restrict__ pose,
                                             const float* __restrict__ ws,
                                             float* __restrict__ out_pf,
                                             float* __restrict__ out_A,
                                             int B) {
  __shared__ float pf_s[64 * 36];
  __shared__ float A_s[64 * 80];
  int t = threadIdx.x;
  int b0 = blockIdx.x * 64;
  int b = b0 + t;
  const float* wsJ = ws + WSJ;

  if (b < B) {
    float R[5][9];
#pragma unroll
    for (int j = 0; j < 5; ++j) {
      float x = pose[b * 15 + j * 3 + 0];
      float y = pose[b * 15 + j * 3 + 1];
      float z = pose[b * 15 + j * 3 + 2];
      float ax = x + 1e-8f, ay = y + 1e-8f, az = z + 1e-8f;
      float ang = sqrtf(ax * ax + ay * ay + az * az);
      float inv = 1.0f / ang;
      float ux = x * inv, uy = y * inv, uz = z * inv;
      float s = __sinf(ang), c = __cosf(ang), t1 = 1.0f - c;
      R[j][0] = 1.0f - t1 * (uy * uy + uz * uz);
      R[j][1] = t1 * ux * uy - s * uz;
      R[j][2] = t1 * ux * uz + s * uy;
      R[j][3] = t1 * ux * uy + s * uz;
      R[j][4] = 1.0f - t1 * (ux * ux + uz * uz);
      R[j][5] = t1 * uy * uz - s * ux;
      R[j][6] = t1 * ux * uz - s * uy;
      R[j][7] = t1 * uy * uz + s * ux;
      R[j][8] = 1.0f - t1 * (ux * ux + uy * uy);
    }

#pragma unroll
    for (int j = 1; j < 5; ++j)
#pragma unroll
      for (int i = 0; i < 9; ++i)
        pf_s[t * 36 + (j - 1) * 9 + i] =
            R[j][i] - ((i == 0 || i == 4 || i == 8) ? 1.0f : 0.0f);

    float jnt[5][3];
#pragma unroll
    for (int j = 0; j < 5; ++j)
#pragma unroll
      for (int k = 0; k < 3; ++k) jnt[j][k] = wsJ[j * 160 + 150 + k];
    for (int e = 0; e < NEXP; ++e) {
      float ex = expr[b * NEXP + e];
#pragma unroll
      for (int j = 0; j < 5; ++j)
#pragma unroll
        for (int k = 0; k < 3; ++k)
          jnt[j][k] = fmaf(ex, wsJ[j * 160 + k * 50 + e], jnt[j][k]);
    }

    float* Ab = A_s + t * 80;
#pragma unroll
    for (int r = 0; r < 3; ++r) {
      float tj = R[0][r * 3 + 0] * jnt[0][0] + R[0][r * 3 + 1] * jnt[0][1] +
                 R[0][r * 3 + 2] * jnt[0][2];
      Ab[r * 4 + 0] = R[0][r * 3 + 0];
      Ab[r * 4 + 1] = R[0][r * 3 + 1];
      Ab[r * 4 + 2] = R[0][r * 3 + 2];
      Ab[r * 4 + 3] = jnt[0][r] - tj;
    }
    Ab[12] = 0.f; Ab[13] = 0.f; Ab[14] = 0.f; Ab[15] = 1.f;

    float C1R[9], C1t[3];
    {
      float rel[3] = {jnt[1][0] - jnt[0][0], jnt[1][1] - jnt[0][1],
                      jnt[1][2] - jnt[0][2]};
#pragma unroll
      for (int r = 0; r < 3; ++r) {
#pragma unroll
        for (int c = 0; c < 3; ++c)
          C1R[r * 3 + c] = R[0][r * 3 + 0] * R[1][0 + c] +
                           R[0][r * 3 + 1] * R[1][3 + c] +
                           R[0][r * 3 + 2] * R[1][6 + c];
        C1t[r] = R[0][r * 3 + 0] * rel[0] + R[0][r * 3 + 1] * rel[1] +
                 R[0][r * 3 + 2] * rel[2] + jnt[0][r];
      }
      float* A1 = Ab + 16;
#pragma unroll
      for (int r = 0; r < 3; ++r) {
        float tj = C1R[r * 3 + 0] * jnt[1][0] + C1R[r * 3 + 1] * jnt[1][1] +
                   C1R[r * 3 + 2] * jnt[1][2];
        A1[r * 4 + 0] = C1R[r * 3 + 0];
        A1[r * 4 + 1] = C1R[r * 3 + 1];
        A1[r * 4 + 2] = C1R[r * 3 + 2];
        A1[r * 4 + 3] = C1t[r] - tj;
      }
      A1[12] = 0.f; A1[13] = 0.f; A1[14] = 0.f; A1[15] = 1.f;
    }

#pragma unroll
    for (int i = 2; i < 5; ++i) {
      float rel[3] = {jnt[i][0] - jnt[1][0], jnt[i][1] - jnt[1][1],
                      jnt[i][2] - jnt[1][2]};
      float CiR[9], Cit[3];
#pragma unroll
      for (int r = 0; r < 3; ++r) {
#pragma unroll
        for (int c = 0; c < 3; ++c)
          CiR[r * 3 + c] = C1R[r * 3 + 0] * R[i][0 + c] +
                           C1R[r * 3 + 1] * R[i][3 + c] +
                           C1R[r * 3 + 2] * R[i][6 + c];
        Cit[r] = C1R[r * 3 + 0] * rel[0] + C1R[r * 3 + 1] * rel[1] +
                 C1R[r * 3 + 2] * rel[2] + C1t[r];
      }
      float* Ai = Ab + i * 16;
#pragma unroll
      for (int r = 0; r < 3; ++r) {
        float tj = CiR[r * 3 + 0] * jnt[i][0] + CiR[r * 3 + 1] * jnt[i][1] +
                   CiR[r * 3 + 2] * jnt[i][2];
        Ai[r * 4 + 0] = CiR[r * 3 + 0];
        Ai[r * 4 + 1] = CiR[r * 3 + 1];
        Ai[r * 4 + 2] = CiR[r * 3 + 2];
        Ai[r * 4 + 3] = Cit[r] - tj;
      }
      Ai[12] = 0.f; Ai[13] = 0.f; Ai[14] = 0.f; Ai[15] = 1.f;
    }
  }
  __syncthreads();
  // coalesced copy-out
  for (int r = 0; r < 36; ++r)
    out_pf[(size_t)b0 * 36 + r * 64 + t] = pf_s[r * 64 + t];
  for (int r = 0; r < 80; ++r)
    out_A[(size_t)b0 * 80 + r * 64 + t] = A_s[r * 64 + t];
}

// LDS-tiled GEMM (K=86 resident) + fused skinning epilogue.
// Block: 64 batches x 120 cols (40 verts). 256 threads; thread tile 4b x 8i.
#define BM 64
#define BN 120
#define KK 86
#define GSTR 68
#define CSTR 124
__global__ __launch_bounds__(256) void k_vert(const float* __restrict__ expr,
                                              const float* __restrict__ vt,
                                              const float* __restrict__ sd,
                                              const float* __restrict__ pd,
                                              const float* __restrict__ w,
                                              const float* __restrict__ pf,
                                              const float* __restrict__ A,
                                              float* __restrict__ out, int B) {
  __shared__ float Gs[KK * GSTR];        // 23392 B; A-tile overlay (5120 f)
  __shared__ float Ss[KK * BN + 8];      // 41312 B; C-tile overlay (64*124 f)
  int tid = threadIdx.x;
  int tx = tid & 15;    // i-thread (active < 15)
  int ty = tid >> 4;    // b-thread
  int i0 = blockIdx.x * BN;
  int b0 = blockIdx.y * BM;
  int vbase = i0 / 3;

  // ---- stage S[86][120]: rows 0..49 from shapedirs cols, 50..85 from posedirs
  for (int idx = tid; idx < 22 * BN; idx += 256) {
    int rq = idx / BN, col = idx - rq * BN;
    int ig = min(i0 + col, NV3 - 1);
    int v = ig / 3, kc = ig - 3 * v;
#pragma unroll
    for (int q = 0; q < 4; ++q) {
      int r = rq * 4 + q;
      if (r < KK) {
        float val = (r < 50) ? sd[(size_t)v * 450 + kc * 150 + 100 + r]
                             : pd[(size_t)(r - 50) * NV3 + ig];
        Ss[r * BN + col] = val;
      }
    }
  }
  // ---- stage G[86][64] transposed (k-major)
  for (int idx = tid; idx < KK * BM; idx += 256) {
    int k = idx >> 6, bb = idx & 63;
    float val = (k < 50) ? expr[(size_t)(b0 + bb) * 50 + k]
                         : pf[(size_t)(b0 + bb) * 36 + (k - 50)];
    Gs[k * GSTR + bb] = val;
  }
  // ---- acc init = v_template
  float vtv[8];
#pragma unroll
  for (int n = 0; n < 8; ++n)
    vtv[n] = vt[min(i0 + 8 * tx + n, NV3 - 1)];
  float acc[4][8];
#pragma unroll
  for (int m = 0; m < 4; ++m)
#pragma unroll
    for (int n = 0; n < 8; ++n) acc[m][n] = vtv[n];
  __syncthreads();

  // ---- GEMM: acc += G^T S
#pragma unroll 2
  for (int k = 0; k < KK; ++k) {
    float4 g  = *(const float4*)&Gs[k * GSTR + 4 * ty];
    float4 s0 = *(const float4*)&Ss[k * BN + 8 * tx];
    float4 s1 = *(const float4*)&Ss[k * BN + 8 * tx + 4];
    float gm[4] = {g.x, g.y, g.z, g.w};
    float sn[8] = {s0.x, s0.y, s0.z, s0.w, s1.x, s1.y, s1.z, s1.w};
#pragma unroll
    for (int m = 0; m < 4; ++m)
#pragma unroll
      for (int n = 0; n < 8; ++n)
        acc[m][n] = fmaf(gm[m], sn[n], acc[m][n]);
  }
  __syncthreads();

  // ---- write C (v_posed) into Ss region; stage A-tile into Gs region
  if (tx < 15) {
#pragma unroll
    for (int m = 0; m < 4; ++m) {
      float4 c0 = {acc[m][0], acc[m][1], acc[m][2], acc[m][3]};
      float4 c1 = {acc[m][4], acc[m][5], acc[m][6], acc[m][7]};
      *(float4*)&Ss[(4 * ty + m) * CSTR + 8 * tx]     = c0;
      *(float4*)&Ss[(4 * ty + m) * CSTR + 8 * tx + 4] = c1;
    }
  }
  for (int idx = tid; idx < BM * 80; idx += 256)
    Gs[idx] = A[(size_t)b0 * 80 + idx];
  __syncthreads();

  // ---- epilogue: skinning. 2560 (b,v) pairs / 256 threads = 10 each
  int nv = min(40, NVERT - vbase);
#pragma unroll
  for (int p = 0; p < 10; ++p) {
    int P = tid + p * 256;
    int v = P % 40, bb = P / 40;
    if (v >= nv) continue;
    const float* wp = w + (size_t)(vbase + v) * 5;
    float w0 = wp[0], w1 = wp[1], w2 = wp[2], w3 = wp[3], w4 = wp[4];
    const float* Ab = Gs + bb * 80;
    float T[12];
#pragma unroll
    for (int rc = 0; rc < 12; ++rc) T[rc] = w0 * Ab[rc];
#pragma unroll
    for (int rc = 0; rc < 12; ++rc) T[rc] = fmaf(w1, Ab[16 + rc], T[rc]);
#pragma unroll
    for (int rc = 0; rc < 12; ++rc) T[rc] = fmaf(w2, Ab[32 + rc], T[rc]);
#pragma unroll
    for (int rc = 0; rc < 12; ++rc) T[rc] = fmaf(w3, Ab[48 + rc], T[rc]);
#pragma unroll
    for (int rc = 0; rc < 12; ++rc) T[rc] = fmaf(w4, Ab[64 + rc], T[rc]);
    float x0 = Ss[bb * CSTR + 3 * v + 0];
    float x1 = Ss[bb * CSTR + 3 * v + 1];
    float x2 = Ss[bb * CSTR + 3 * v + 2];
    size_t ob = (size_t)(b0 + bb) * NV3 + i0 + 3 * v;
#pragma unroll
    for (int q = 0; q < 3; ++q)
      out[ob + q] = fmaf(T[q * 4 + 0], x0,
                    fmaf(T[q * 4 + 1], x1,
                    fmaf(T[q * 4 + 2], x2, T[q * 4 + 3])));
  }
}

extern "C" void kernel_launch(void* const* d_in, const int* in_sizes, int n_in,
                              void* d_out, int out_size, void* d_ws,
                              size_t ws_size, hipStream_t stream) {
  const float* expr = (const float*)d_in[0];
  const float* pose = (const float*)d_in[1];
  const float* vt   = (const float*)d_in[2];
  const float* sd   = (const float*)d_in[3];
  const float* pd   = (const float*)d_in[4];
  const float* Jr   = (const float*)d_in[5];
  const float* w    = (const float*)d_in[6];
  int B = in_sizes[0] / NEXP;

  float* out    = (float*)d_out;
  float* out_pf = out + (size_t)B * NV3;
  float* out_A  = out_pf + (size_t)B * NPF;
  float* ws     = (float*)d_ws;

  k_jreg<<<dim3(JBLK), 160, 0, stream>>>(Jr, sd, vt, ws);
  k_jred<<<dim3(3), 256, 0, stream>>>(ws);
  k_pose<<<dim3((B + 63) / 64), 64, 0, stream>>>(expr, pose, ws, out_pf,
                                                 out_A, B);
  k_vert<<<dim3((NV3 + BN - 1) / BN, (B + BM - 1) / BM), 256, 0, stream>>>(
      expr, vt, sd, pd, w, out_pf, out_A, out, B);
}